// Round 7
// baseline (187.047 us; speedup 1.0000x reference)
//
#include <hip/hip_runtime.h>

#define CC 256
#define HH 96
#define WW 128
#define PP 9
#define OFF 4
#define PLANE (HH * WW)      // 12288

#define HB 3                 // output rows per WG
#define PX 32                // output px per WG
#define SW 48                // staged in2 cols (32 + 16 halo)
#define PAD 20               // u32 stride per px (16 c-pairs + 4 pad)
#define KCH 32               // channels per chunk = MFMA K
#define NCHK (CC / KCH)      // 8
#define TPB 384              // 6 waves = 3 rows x 2 px1-blocks
#define RNMAX 7              // staged in2 rows (dy-half A: 7, B: 6)
#define DPAD 36              // f32 px1-stride in D scratch
#define NU 4                 // in2 staging units per thread
#define ADVB (KCH * PLANE * 4)   // byte advance per chunk

typedef _Float16 f16x8 __attribute__((ext_vector_type(8)));
typedef float fx4 __attribute__((ext_vector_type(4)));

union U16 { uint4 u; f16x8 h; };

__device__ __forceinline__ unsigned pk(float a, float b) {
#if __has_builtin(__builtin_amdgcn_cvt_pkrtz)
  auto r = __builtin_amdgcn_cvt_pkrtz(a, b);
  unsigned u; __builtin_memcpy(&u, &r, 4); return u;
#else
  _Float16 h0 = (_Float16)a, h1 = (_Float16)b;
  unsigned u = 0, v = 0; __builtin_memcpy(&u, &h0, 2); __builtin_memcpy(&v, &h1, 2);
  return u | (v << 16);
#endif
}

// MFMA formulation (validated round 3): D[px1,px2] = sum_c in1[c,px1]*in2[c,px2];
// out(dy,dx,px1) = D_dy[px1, px1+dx-4].
// Round 7: break the stage/compute phase convoy. Evidence: fetch-rate is pinned
// at ~1.13 TB/s across R3/R6 regardless of occupancy -> memory is only active
// during the staging window between barriers. Fix: double-buffered LDS as TWO
// separate __shared__ objects (compile-time parity, unrolled x2) so the
// scheduler can PROVE no aliasing and interleave STAGE(c+1 -> buf B) with
// COMPUTE(c, buf A) inside each wave. One barrier per chunk; no registers live
// across any barrier; no sched_barrier pins (they would block the interleave).
__global__ __launch_bounds__(TPB, 3) void corr_kernel(const float* __restrict__ in1,
                                                      const float* __restrict__ in2,
                                                      float* __restrict__ out) {
  __shared__ __align__(16) unsigned s2a[RNMAX][SW][PAD];  // 26880 B
  __shared__ __align__(16) unsigned s1a[HB][PX][PAD];     //  7680 B
  __shared__ __align__(16) unsigned s2b[RNMAX][SW][PAD];  // 26880 B
  __shared__ __align__(16) unsigned s1b[HB][PX][PAD];     //  7680 B -> 69.1 KB

  // 1024 WGs: XCD k owns bands 4k..4k+3; both dy-halves of a band on same XCD.
  const int bx = blockIdx.x;
  const int xcd = bx & 7;
  const int s = bx >> 3;           // 0..127
  const int half = s & 1;          // dy-half
  const int xq = (s >> 1) & 3;
  const int b = (s >> 3) & 3;
  const int bl = s >> 5;           // 0..3
  const int band = xcd * 4 + bl;
  const int h0 = band * HB;
  const int d0 = half ? 5 : 0;     // first dy of this WG
  const int ndy = half ? 4 : 5;    // dy count (block-uniform)
  const int rnw = ndy + HB - 1;    // staged rows: 7 (A) / 6 (B)

  const int tid = threadIdx.x;
  const int wv = tid >> 6;
  const int wr = wv >> 1;          // row 0..2
  const int wp = wv & 1;           // px1-block 0..1
  const int lane = tid & 63;
  const int ln = lane & 15;        // MFMA m/n index
  const int lg = lane >> 4;        // MFMA k-group

  const char* in2p = (const char*)in2;
  const char* in1p = (const char*)in1;

  // ---- in2 staging roles (validated mapping): spx 0..47, scb c-block, sr0.
  const int spx = tid % 48;
  const int sq = tid / 48;         // 0..7
  const int scb = sq & 3;          // c-block (8 channels)
  const int sr0 = sq >> 2;         // 0..1; unit k covers row r = sr0 + 2k
  const int gx2 = xq * PX - OFF + spx;
  const bool okx = (unsigned)gx2 < WW;

  unsigned o2[NU];                 // byte offsets (valid units only)
  unsigned vmask = 0;
#pragma unroll
  for (int k = 0; k < NU; ++k) {
    const int r = sr0 + 2 * k;                 // slot in s2
    const int rg = h0 - OFF + d0 + r;          // global row
    const bool ok = (r < rnw) && okx && ((unsigned)rg < HH);
    o2[k] = ok ? (unsigned)(((b * CC + scb * 8) * PLANE + rg * WW + gx2) * 4) : 0u;
    vmask |= (ok ? 1u : 0u) << k;
  }
  // ---- in1 staging role: 1 b128-unit/thread, always in-bounds.
  const int tpx = tid & 31;
  const int tq = tid >> 5;         // 0..11
  const int tcb = tq & 3;
  const int tr = tq >> 2;          // 0..2
  const unsigned o1 = (unsigned)(((b * CC + tcb * 8) * PLANE + (h0 + tr) * WW + xq * PX + tpx) * 4);

  // pre-zero BOTH s2 buffers: OOB halo slots stay zero forever
  for (int i = tid; i < RNMAX * SW * PAD; i += TPB) {
    ((unsigned*)s2a)[i] = 0u;
    ((unsigned*)s2b)[i] = 0u;
  }

  fx4 acc[5][2];
#pragma unroll
  for (int d = 0; d < 5; ++d)
#pragma unroll
    for (int t = 0; t < 2; ++t) acc[d][t] = (fx4)0.f;

  // STAGE: self-contained load->pk->store (no cross-barrier registers)
  auto STAGE = [&](unsigned (&S2)[RNMAX][SW][PAD], unsigned (&S1)[HB][PX][PAD], int c) {
    const unsigned cadv = (unsigned)c * (unsigned)ADVB;
#pragma unroll
    for (int k = 0; k < NU; ++k)
      if ((vmask >> k) & 1) {
        const float* p = (const float*)(in2p + (o2[k] + cadv));
        const float l0 = p[0], l1 = p[PLANE], l2 = p[2 * PLANE], l3 = p[3 * PLANE];
        const float l4 = p[4 * PLANE], l5 = p[5 * PLANE], l6 = p[6 * PLANE], l7 = p[7 * PLANE];
        uint4 w;
        w.x = pk(l0, l1); w.y = pk(l2, l3); w.z = pk(l4, l5); w.w = pk(l6, l7);
        *(uint4*)&S2[sr0 + 2 * k][spx][4 * scb] = w;
      }
    {
      const float* p = (const float*)(in1p + (o1 + cadv));
      const float l0 = p[0], l1 = p[PLANE], l2 = p[2 * PLANE], l3 = p[3 * PLANE];
      const float l4 = p[4 * PLANE], l5 = p[5 * PLANE], l6 = p[6 * PLANE], l7 = p[7 * PLANE];
      uint4 w;
      w.x = pk(l0, l1); w.y = pk(l2, l3); w.z = pk(l4, l5); w.w = pk(l6, l7);
      *(uint4*)&S1[tr][tpx][4 * tcb] = w;
    }
  };

  auto COMPUTE = [&](const unsigned (&S2)[RNMAX][SW][PAD], const unsigned (&S1)[HB][PX][PAD]) {
    U16 a; a.u = *(const uint4*)&S1[wr][wp * 16 + ln][4 * lg];
#pragma unroll
    for (int d = 0; d < 5; ++d)
      if (d < ndy) {               // block-uniform guard; acc index static
#pragma unroll
        for (int t = 0; t < 2; ++t) {
          U16 bb; bb.u = *(const uint4*)&S2[wr + d][wp * 16 + 16 * t + ln][4 * lg];
          acc[d][t] = __builtin_amdgcn_mfma_f32_16x16x32_f16(a.h, bb.h, acc[d][t], 0, 0, 0);
        }
      }
  };

  __syncthreads();                 // pre-zero visible
  STAGE(s2a, s1a, 0);
  __syncthreads();                 // chunk 0 visible

  // ---- main loop: 2 chunks per iteration, compile-time buffer parity,
  // STAGE(next, other-buf) textually before COMPUTE(cur) -> scheduler
  // interleaves loads with MFMA (distinct __shared__ objects, no alias).
#pragma unroll 1
  for (int cc = 0; cc < NCHK / 2; ++cc) {
    STAGE(s2b, s1b, 2 * cc + 1);
    COMPUTE(s2a, s1a);
    __syncthreads();
    if (cc < NCHK / 2 - 1) STAGE(s2a, s1a, 2 * cc + 2);
    COMPUTE(s2b, s1b);
    __syncthreads();
  }

  // ---- epilogue: ping-pong D-slices across the two buffers.
  // D layout: col(n=px2) = lane&15, row(m=px1) = (lane>>4)*4 + reg.
  auto WRITED = [&](float* DL, const fx4 (&ad)[2]) {
#pragma unroll
    for (int t = 0; t < 2; ++t) {
      const int p2 = wp * 16 + 16 * t + ln;
      *(fx4*)&DL[(wr * SW + p2) * DPAD + wp * 16 + 4 * lg] = ad[t];
    }
  };
  auto READOUT = [&](const float* DL, int dyg) {
#pragma unroll
    for (int k2 = 0; k2 < 3; ++k2) {
      const int id = tid + TPB * k2;
      if (id < HB * PP * PX) {
        const int px = id & 31;
        const int v = id >> 5;       // 0..26
        const int dx = v % PP;
        const int rr = v / PP;
        out[(size_t)((b * PP + dyg) * PP + dx) * PLANE + (size_t)(h0 + rr) * WW + xq * PX + px] =
            DL[(rr * SW + px + dx) * DPAD + px];  // px2w = px1 + dx - 4 + 4halo
      }
    }
  };

  float* DLA = (float*)&s2a[0][0][0];  // 5184 f32 = 20.7 KB <= 26.9 KB each
  float* DLB = (float*)&s2b[0][0][0];

  WRITED(DLA, acc[0]);
  __syncthreads();
  if (1 < ndy) WRITED(DLB, acc[1]);
  READOUT(DLA, d0 + 0);
  __syncthreads();
  if (2 < ndy) WRITED(DLA, acc[2]);
  if (1 < ndy) READOUT(DLB, d0 + 1);
  __syncthreads();
  if (3 < ndy) WRITED(DLB, acc[3]);
  if (2 < ndy) READOUT(DLA, d0 + 2);
  __syncthreads();
  if (4 < ndy) WRITED(DLA, acc[4]);
  if (3 < ndy) READOUT(DLB, d0 + 3);
  __syncthreads();
  if (4 < ndy) READOUT(DLA, d0 + 4);
}

extern "C" void kernel_launch(void* const* d_in, const int* in_sizes, int n_in,
                              void* d_out, int out_size, void* d_ws, size_t ws_size,
                              hipStream_t stream) {
  const float* in1 = (const float*)d_in[0];
  const float* in2 = (const float*)d_in[1];
  float* out = (float*)d_out;
  // 1024 blocks = 4b * 32 bands * 4 xq * 2 dy-halves (xcd-swizzled)
  corr_kernel<<<dim3(1024), dim3(TPB), 0, stream>>>(in1, in2, out);
}